// Round 20
// baseline (413.340 us; speedup 1.0000x reference)
//
#include <hip/hip_runtime.h>
#include <math.h>

#define EPSF 1e-6f

__device__ __constant__ int DISK[37] = {
    2, 3, 4,
    8, 9, 10, 11, 12,
    14, 15, 16, 17, 18, 19, 20,
    21, 22, 23, 24, 25, 26, 27,
    28, 29, 30, 31, 32, 33, 34,
    36, 37, 38, 39, 40,
    44, 45, 46};

// ---------------------------------------------------------------------------
// g[n, d, rm] = sum_c Wc[d, c, rm] * x[n, c];  Wc = W_conv * exp(i*phase)
// ---------------------------------------------------------------------------
__global__ __launch_bounds__(256) void g_kernel(
    const float* __restrict__ x_re, const float* __restrict__ x_im,
    const float* __restrict__ W_conv, const float* __restrict__ phase,
    float2* __restrict__ g2, int N) {
  __shared__ float wc_re[1152];
  __shared__ float wc_im[1152];
  int t = threadIdx.x;
  for (int i = t; i < 1152; i += 256) {
    int dc = i / 18;
    float w = W_conv[i];
    float ph = phase[dc];
    wc_re[i] = w * cosf(ph);
    wc_im[i] = w * sinf(ph);
  }
  __syncthreads();
  int gid = blockIdx.x * 256 + t;
  int total = N * 72;  // (n, d, p) pairs; each covers rm=2p, 2p+1
  if (gid >= total) return;
  int n = gid / 72;
  int q = gid - n * 72;  // d*9 + p
  int d = q / 9;
  int p = q - d * 9;
  int rm = 2 * p;
  const float* xr = x_re + n * 8;
  const float* xi = x_im + n * 8;
  float ar0 = 0.f, ai0 = 0.f, ar1 = 0.f, ai1 = 0.f;
#pragma unroll
  for (int c = 0; c < 8; ++c) {
    int base = (d * 8 + c) * 18 + rm;
    float vr = xr[c], vi = xi[c];
    float wr0 = wc_re[base], wi0 = wc_im[base];
    ar0 += wr0 * vr - wi0 * vi;
    ai0 += wr0 * vi + wi0 * vr;
    float wr1 = wc_re[base + 1], wi1 = wc_im[base + 1];
    ar1 += wr1 * vr - wi1 * vi;
    ai1 += wr1 * vi + wi1 * vr;
  }
  float4 outv = make_float4(ar0, ai0, ar1, ai1);
  *(float4*)(g2 + (size_t)n * 144 + d * 18 + rm) = outv;
}

// ---------------------------------------------------------------------------
// CSR build: count degrees AND capture each edge's rank within its bucket.
// ---------------------------------------------------------------------------
__global__ __launch_bounds__(256) void count_kernel(const int* __restrict__ edges,
                                                    int* __restrict__ cnt,
                                                    int* __restrict__ scnt,
                                                    int* __restrict__ rank,
                                                    int* __restrict__ srank, int E) {
  int e = blockIdx.x * 256 + threadIdx.x;
  if (e >= E) return;
  int2 ed = ((const int2*)edges)[e];
  rank[e] = atomicAdd(&cnt[ed.y], 1);
  srank[e] = atomicAdd(&scnt[ed.x], 1);
}

// Single-block dual exclusive scan: cnt->offs and scnt->soffs
__global__ __launch_bounds__(1024) void scan_dual_kernel(
    const int* __restrict__ cnt, int* __restrict__ offs,
    const int* __restrict__ scnt, int* __restrict__ soffs, int N) {
  __shared__ int sums[1024];
  int t = threadIdx.x;
  int per = (N + 1023) / 1024;
  for (int pass = 0; pass < 2; ++pass) {
    const int* c = pass ? scnt : cnt;
    int* o = pass ? soffs : offs;
    int base = t * per;
    int s = 0;
    for (int i = 0; i < per; ++i) {
      int idx = base + i;
      if (idx < N) s += c[idx];
    }
    sums[t] = s;
    __syncthreads();
    for (int d = 1; d < 1024; d <<= 1) {
      int v = (t >= d) ? sums[t - d] : 0;
      __syncthreads();
      sums[t] += v;
      __syncthreads();
    }
    int run = (t == 0) ? 0 : sums[t - 1];
    for (int i = 0; i < per; ++i) {
      int idx = base + i;
      if (idx < N) {
        int cc = c[idx];
        o[idx] = run;
        run += cc;
      }
    }
    if (t == 1023) o[N] = sums[1023];
    __syncthreads();
  }
}

// fill: atomic-free pure scatter with non-temporal stores.
__global__ __launch_bounds__(256) void fill_kernel(
    const int* __restrict__ edges, const int* __restrict__ offs,
    const int* __restrict__ soffs, const int* __restrict__ rank,
    const int* __restrict__ srank,
    const float* __restrict__ wxp_re, const float* __restrict__ wxp_im,
    const float* __restrict__ ln_re, const float* __restrict__ ln_im,
    int* __restrict__ pay5, int2* __restrict__ scomb, int E) {
  int e = blockIdx.x * 256 + threadIdx.x;
  if (e >= E) return;
  int2 ed = ((const int2*)edges)[e];
  int pos = offs[ed.y] + rank[e];
  int pos2 = soffs[ed.x] + srank[e];
  int* p = pay5 + (size_t)pos * 5;
  __builtin_nontemporal_store(ed.x, p);
  __builtin_nontemporal_store(__float_as_int(wxp_re[e]), p + 1);
  __builtin_nontemporal_store(__float_as_int(wxp_im[e]), p + 2);
  __builtin_nontemporal_store(__float_as_int(ln_re[e]), p + 3);
  __builtin_nontemporal_store(__float_as_int(ln_im[e]), p + 4);
  int2 sc = make_int2(e, pos);
  __builtin_nontemporal_store(*(long long*)&sc, (long long*)(scomb + pos2));
}

// ---------------------------------------------------------------------------
// Edge conv, src-grouped, 2-deep software pipeline (R19) at full occupancy
// (256,4): VGPR=68 fits the 128 budget, so ILP and TLP compose.
// ---------------------------------------------------------------------------
__global__ __launch_bounds__(256, 4) void conv_src_kernel(
    const int* __restrict__ soffs, const int2* __restrict__ scomb,
    const float* __restrict__ sten_re, const float* __restrict__ sten_im,
    const float2* __restrict__ g2, float2* __restrict__ yebuf, int N) {
  int t = threadIdx.x;
  int m = blockIdx.x * 4 + (t >> 6);
  if (m >= N) return;
  int lane = t & 63;
  int es = lane >> 3;
  int d = lane & 7;
  float gr[18], gi[18];
  const float4* gq = (const float4*)(g2 + (size_t)m * 144 + d * 18);
#pragma unroll
  for (int p = 0; p < 9; ++p) {
    float4 v = gq[p];
    gr[2 * p] = v.x; gi[2 * p] = v.y;
    gr[2 * p + 1] = v.z; gi[2 * p + 1] = v.w;
  }

  auto loadSten = [&](int e, float sr[18], float si[18]) {
    const float* br = sten_re + (size_t)e * 18;
    const float* bi = sten_im + (size_t)e * 18;
    float4 r0 = *(const float4*)(br);
    float4 r1 = *(const float4*)(br + 4);
    float4 r2 = *(const float4*)(br + 8);
    float4 r3 = *(const float4*)(br + 12);
    float2 r4 = *(const float2*)(br + 16);
    float4 m0 = *(const float4*)(bi);
    float4 m1 = *(const float4*)(bi + 4);
    float4 m2 = *(const float4*)(bi + 8);
    float4 m3 = *(const float4*)(bi + 12);
    float2 m4 = *(const float2*)(bi + 16);
    sr[0] = r0.x; sr[1] = r0.y; sr[2] = r0.z; sr[3] = r0.w;
    sr[4] = r1.x; sr[5] = r1.y; sr[6] = r1.z; sr[7] = r1.w;
    sr[8] = r2.x; sr[9] = r2.y; sr[10] = r2.z; sr[11] = r2.w;
    sr[12] = r3.x; sr[13] = r3.y; sr[14] = r3.z; sr[15] = r3.w;
    sr[16] = r4.x; sr[17] = r4.y;
    si[0] = m0.x; si[1] = m0.y; si[2] = m0.z; si[3] = m0.w;
    si[4] = m1.x; si[5] = m1.y; si[6] = m1.z; si[7] = m1.w;
    si[8] = m2.x; si[9] = m2.y; si[10] = m2.z; si[11] = m2.w;
    si[12] = m3.x; si[13] = m3.y; si[14] = m3.z; si[15] = m3.w;
    si[16] = m4.x; si[17] = m4.y;
  };
  auto computeStore = [&](int ds, const float sr[18], const float si[18]) {
    float ar = 0.f, ai = 0.f;
#pragma unroll
    for (int rm = 0; rm < 18; ++rm) {
      ar += sr[rm] * gr[rm] - si[rm] * gi[rm];
      ai += sr[rm] * gi[rm] + si[rm] * gr[rm];
    }
    float2 v = make_float2(ar, ai);
    __builtin_nontemporal_store(*(long long*)&v,
                                (long long*)(yebuf + (size_t)ds * 8 + d));
  };

  int beg = soffs[m], end = soffs[m + 1];
  int i = beg + es;
  if (i >= end) return;
  float srA[18], siA[18], srB[18], siB[18];
  int2 sc0 = scomb[i];          // current payload (stencil -> A)
  loadSten(sc0.x, srA, siA);
  int j = i + 8;
  bool hasJ = j < end;
  int2 sc1 = make_int2(0, 0);
  if (hasJ) sc1 = scomb[j];

  for (;;) {
    // current = slot with payload sc0, stencil in A
    if (hasJ) loadSten(sc1.x, srB, siB);   // next stencil in flight
    int k = j + 8;
    bool hasK = hasJ && (k < end);
    int2 sc2 = make_int2(0, 0);
    if (hasK) sc2 = scomb[k];              // prefetch next-next payload
    computeStore(sc0.y, srA, siA);
    if (!hasJ) break;

    // current = slot with payload sc1, stencil in B
    if (hasK) loadSten(sc2.x, srA, siA);
    int l = k + 8;
    bool hasL = hasK && (l < end);
    int2 sc3 = make_int2(0, 0);
    if (hasL) sc3 = scomb[l];
    computeStore(sc1.y, srB, siB);
    if (!hasK) break;

    sc0 = sc2; sc1 = sc3; j = l; hasJ = hasL;
  }
}

// ---------------------------------------------------------------------------
// Reduce ye over each node's contiguous dst-slot range + nonlinearity -> y.
// ---------------------------------------------------------------------------
__global__ __launch_bounds__(256, 4) void ye_reduce_kernel(
    const int* __restrict__ offs, const float2* __restrict__ yebuf,
    const float* __restrict__ b_nl, float* __restrict__ y, int N) {
  int t = threadIdx.x;
  int n = blockIdx.x * 4 + (t >> 6);
  if (n >= N) return;
  int lane = t & 63;
  int es = lane >> 3;
  int d = lane & 7;
  int beg = offs[n], end = offs[n + 1];
  float ar = 0.f, ai = 0.f;
  for (int i = beg + es; i < end; i += 8) {
    long long raw = __builtin_nontemporal_load(
        (const long long*)(yebuf + (size_t)i * 8 + d));
    float2 v = *(float2*)&raw;
    ar += v.x;
    ai += v.y;
  }
  ar += __shfl_xor(ar, 8);
  ai += __shfl_xor(ai, 8);
  ar += __shfl_xor(ar, 16);
  ai += __shfl_xor(ai, 16);
  ar += __shfl_xor(ar, 32);
  ai += __shfl_xor(ai, 32);
  if (lane < 8) {
    float mag = sqrtf(ar * ar + ai * ai);
    float s = fmaxf(mag + b_nl[d], 0.f) / (mag + EPSF);
    y[(size_t)n * 16 + 2 * d] = ar * s;
    y[(size_t)n * 16 + 2 * d + 1] = ai * s;
  }
}

// ---------------------------------------------------------------------------
// Histogram, ZERO FP atomics: per-thread exclusive 51-word LDS strip.
// (R18-exact, measured best.)
// ---------------------------------------------------------------------------
__global__ __launch_bounds__(256, 3) void hist_kernel(
    const int* __restrict__ offs, const int* __restrict__ pay5,
    const float* __restrict__ y, float* __restrict__ desc_g, int N) {
  __shared__ float hl[256 * 51];  // 52.2 KB
  int t = threadIdx.x;
  int n0 = blockIdx.x * 8;
  for (int i = t; i < 256 * 51; i += 256) hl[i] = 0.f;
  __syncthreads();

  int v = t >> 5;
  int es = (t >> 3) & 3;
  int d = t & 7;
  int n = n0 + v;
  float* hd = hl + (size_t)t * 51;
  if (n < N) {
    int beg = offs[n], end = offs[n + 1];
    for (int i = beg + es; i < end; i += 4) {
      const int* p = pay5 + (size_t)i * 5;
      int src = p[0];
      float wr = __int_as_float(p[1]);
      float wi = __int_as_float(p[2]);
      float lr = __int_as_float(p[3]);
      float li = __int_as_float(p[4]);
      float2 yv = *(const float2*)(y + (size_t)src * 16 + 2 * d);
      float yr = yv.x, yi = yv.y;
      float fr = yr * wr - yi * wi;
      float fi = yr * wi + yi * wr;
      float fm = sqrtf(fr * fr + fi * fi);
      float inv = 1.f / (fm + EPSF);
      float cr = (lr * fr + li * fi) * inv;
      float ci = (li * fr - lr * fi) * inv;
      float gx = cr * 3.f + 3.f;
      float gy = ci * 3.f + 3.f;
      float x0f = floorf(gx), y0f = floorf(gy);
      float wx = gx - x0f, wy = gy - y0f;
      int x0i = min(max((int)x0f, 0), 6);
      int x1i = min(x0i + 1, 6);
      int y0i = min(max((int)y0f, 0), 6);
      int y1i = min(y0i + 1, 6);
      hd[x0i * 7 + y0i] += fm * (1.f - wx) * (1.f - wy);
      hd[x1i * 7 + y0i] += fm * wx * (1.f - wy);
      hd[x0i * 7 + y1i] += fm * (1.f - wx) * wy;
      hd[x1i * 7 + y1i] += fm * wx * wy;
    }
  }
  __syncthreads();

  for (int i = t; i < 8 * 296; i += 256) {
    int vv = i / 296;
    int q = i - vv * 296;
    int dd = q / 37;
    int k = q - dd * 37;
    int bin = DISK[k];
    float s = 0.f;
#pragma unroll
    for (int e2 = 0; e2 < 4; ++e2)
      s += hl[(size_t)(vv * 32 + e2 * 8 + dd) * 51 + bin];
    int nn = n0 + vv;
    if (nn < N) desc_g[(size_t)nn * 296 + q] = s;
  }
}

// ---------------------------------------------------------------------------
// mlp1: h1 = relu(desc @ W1^T + b1).  64 nodes/block, 256 threads.
// kk loop pinned no-unroll (prevents unroll-and-hoist spill; R13 verified).
// ---------------------------------------------------------------------------
__global__ __launch_bounds__(256, 4) void mlp1_kernel(
    const float* __restrict__ desc_g, const float* __restrict__ W1,
    const float* __restrict__ b1, float* __restrict__ h1_g, int N) {
  __shared__ float bufA[64 * 40];
  __shared__ float bufB[40 * 133];
  int t = threadIdx.x;
  int n0 = blockIdx.x * 64;
  int jt = t & 31;
  int nb = (t >> 5) * 8;

  float acc[8][4];
#pragma unroll
  for (int jj = 0; jj < 4; ++jj) {
    float bb = b1[jt + 32 * jj];
#pragma unroll
    for (int i = 0; i < 8; ++i) acc[i][jj] = bb;
  }

  for (int k0 = 0; k0 < 296; k0 += 40) {
    int kc = min(40, 296 - k0);
    int kc4 = kc >> 2;
    for (int i = t; i < 64 * kc4; i += 256) {
      int r = i / kc4, c4 = (i - r * kc4) * 4;
      int n = n0 + r;
      float4 v = (n < N) ? *(const float4*)&desc_g[(size_t)n * 296 + k0 + c4]
                         : make_float4(0.f, 0.f, 0.f, 0.f);
      *(float4*)&bufA[r * 40 + c4] = v;
    }
    for (int i = t; i < 128 * kc4; i += 256) {
      int r = i / kc4, c4 = (i - r * kc4) * 4;
      float4 w = *(const float4*)&W1[(size_t)r * 296 + k0 + c4];
      bufB[(c4 + 0) * 133 + r] = w.x;
      bufB[(c4 + 1) * 133 + r] = w.y;
      bufB[(c4 + 2) * 133 + r] = w.z;
      bufB[(c4 + 3) * 133 + r] = w.w;
    }
    __syncthreads();
#pragma unroll 1
    for (int kk = 0; kk < kc; kk += 4) {
      float4 a[8];
#pragma unroll
      for (int i = 0; i < 8; ++i) a[i] = *(const float4*)&bufA[(nb + i) * 40 + kk];
#pragma unroll
      for (int q = 0; q < 4; ++q) {
        float bv[4];
#pragma unroll
        for (int jj = 0; jj < 4; ++jj) bv[jj] = bufB[(kk + q) * 133 + jt + 32 * jj];
#pragma unroll
        for (int i = 0; i < 8; ++i) {
          float av = (q == 0) ? a[i].x : (q == 1) ? a[i].y : (q == 2) ? a[i].z : a[i].w;
#pragma unroll
          for (int jj = 0; jj < 4; ++jj) acc[i][jj] += av * bv[jj];
        }
      }
    }
    __syncthreads();
  }
#pragma unroll
  for (int i = 0; i < 8; ++i) {
    int n = n0 + nb + i;
    if (n < N) {
#pragma unroll
      for (int jj = 0; jj < 4; ++jj)
        h1_g[(size_t)n * 128 + jt + 32 * jj] = fmaxf(acc[i][jj], 0.f);
    }
  }
}

// ---------------------------------------------------------------------------
// mlp23 (R7/R11 structure): separate h2s buffer; kk loops pinned no-unroll.
// ---------------------------------------------------------------------------
__global__ __launch_bounds__(256, 4) void mlp23_kernel(
    const float* __restrict__ h1_g,
    const float* __restrict__ x_re, const float* __restrict__ x_im,
    const float* __restrict__ W2, const float* __restrict__ b2,
    const float* __restrict__ W3, const float* __restrict__ b3,
    const float* __restrict__ Wres, const float* __restrict__ bres,
    float* __restrict__ out, int N) {
  __shared__ float bufA[64 * 68];
  __shared__ float bufB[64 * 67];
  __shared__ float h2s[64 * 68];
  __shared__ float rmag[64][8];
  int t = threadIdx.x;
  int n0 = blockIdx.x * 64;
  int jt = t & 31;
  int nb = (t >> 5) * 8;

  for (int i = t; i < 512; i += 256) {
    int v = i >> 3, c = i & 7;
    int n = n0 + v;
    if (n < N) {
      float xr = x_re[n * 8 + c], xi = x_im[n * 8 + c];
      rmag[v][c] = sqrtf(xr * xr + xi * xi + EPSF);
    } else {
      rmag[v][c] = 0.f;
    }
  }

  // ---------------- Layer 2 ----------------
  float acc2[8][2];
#pragma unroll
  for (int jj = 0; jj < 2; ++jj) {
    float bb = b2[jt + 32 * jj];
#pragma unroll
    for (int i = 0; i < 8; ++i) acc2[i][jj] = bb;
  }
#pragma unroll 1
  for (int k0 = 0; k0 < 128; k0 += 64) {
    for (int i = t; i < 64 * 16; i += 256) {
      int r = i >> 4, c4 = (i & 15) * 4;
      int n = n0 + r;
      float4 v = (n < N) ? *(const float4*)&h1_g[(size_t)n * 128 + k0 + c4]
                         : make_float4(0.f, 0.f, 0.f, 0.f);
      *(float4*)&bufA[r * 68 + c4] = v;
    }
    for (int i = t; i < 64 * 16; i += 256) {
      int r = i >> 4, c4 = (i & 15) * 4;
      float4 w = *(const float4*)&W2[(size_t)r * 128 + k0 + c4];
      bufB[(c4 + 0) * 67 + r] = w.x;
      bufB[(c4 + 1) * 67 + r] = w.y;
      bufB[(c4 + 2) * 67 + r] = w.z;
      bufB[(c4 + 3) * 67 + r] = w.w;
    }
    __syncthreads();
#pragma unroll 1
    for (int kk = 0; kk < 64; kk += 4) {
      float4 a[8];
#pragma unroll
      for (int i = 0; i < 8; ++i) a[i] = *(const float4*)&bufA[(nb + i) * 68 + kk];
#pragma unroll
      for (int q = 0; q < 4; ++q) {
        float bv[2];
#pragma unroll
        for (int jj = 0; jj < 2; ++jj) bv[jj] = bufB[(kk + q) * 67 + jt + 32 * jj];
#pragma unroll
        for (int i = 0; i < 8; ++i) {
          float av = (q == 0) ? a[i].x : (q == 1) ? a[i].y : (q == 2) ? a[i].z : a[i].w;
#pragma unroll
          for (int jj = 0; jj < 2; ++jj) acc2[i][jj] += av * bv[jj];
        }
      }
    }
    __syncthreads();
  }
#pragma unroll
  for (int i = 0; i < 8; ++i)
#pragma unroll
    for (int jj = 0; jj < 2; ++jj)
      h2s[(nb + i) * 68 + jt + 32 * jj] = fmaxf(acc2[i][jj], 0.f);

  // stage W3 k-major (reuse bufB)
  __syncthreads();
  for (int i = t; i < 64 * 16; i += 256) {
    int r = i >> 4, c4 = (i & 15) * 4;
    float4 w = *(const float4*)&W3[(size_t)r * 64 + c4];
    bufB[(c4 + 0) * 67 + r] = w.x;
    bufB[(c4 + 1) * 67 + r] = w.y;
    bufB[(c4 + 2) * 67 + r] = w.z;
    bufB[(c4 + 3) * 67 + r] = w.w;
  }
  __syncthreads();

  // ---------------- Layer 3 + residual ----------------
  float acc3[8][2];
#pragma unroll
  for (int jj = 0; jj < 2; ++jj) {
    float bb = b3[jt + 32 * jj] + bres[jt + 32 * jj];
#pragma unroll
    for (int i = 0; i < 8; ++i) acc3[i][jj] = bb;
  }
#pragma unroll 1
  for (int kk = 0; kk < 64; kk += 4) {
    float4 a[8];
#pragma unroll
    for (int i = 0; i < 8; ++i) a[i] = *(const float4*)&h2s[(nb + i) * 68 + kk];
#pragma unroll
    for (int q = 0; q < 4; ++q) {
      float bv[2];
#pragma unroll
      for (int jj = 0; jj < 2; ++jj) bv[jj] = bufB[(kk + q) * 67 + jt + 32 * jj];
#pragma unroll
      for (int i = 0; i < 8; ++i) {
        float av = (q == 0) ? a[i].x : (q == 1) ? a[i].y : (q == 2) ? a[i].z : a[i].w;
#pragma unroll
        for (int jj = 0; jj < 2; ++jj) acc3[i][jj] += av * bv[jj];
      }
    }
  }
#pragma unroll
  for (int jj = 0; jj < 2; ++jj) {
    int j = jt + 32 * jj;
    float wrr[8];
    const float* wp = Wres + (size_t)j * 8;
#pragma unroll
    for (int c = 0; c < 8; ++c) wrr[c] = wp[c];
#pragma unroll
    for (int i = 0; i < 8; ++i) {
      float s = acc3[i][jj];
#pragma unroll
      for (int c = 0; c < 8; ++c) s += wrr[c] * rmag[nb + i][c];
      int n = n0 + nb + i;
      if (n < N) out[(size_t)n * 64 + j] = s;
    }
  }
}

extern "C" void kernel_launch(void* const* d_in, const int* in_sizes, int n_in,
                              void* d_out, int out_size, void* d_ws, size_t ws_size,
                              hipStream_t stream) {
  (void)n_in; (void)out_size; (void)ws_size;
  const float* x_re = (const float*)d_in[0];
  const float* x_im = (const float*)d_in[1];
  const int* edges = (const int*)d_in[2];
  const float* sten_re = (const float*)d_in[3];
  const float* sten_im = (const float*)d_in[4];
  const float* ln_re = (const float*)d_in[5];
  const float* ln_im = (const float*)d_in[6];
  const float* wxp_re = (const float*)d_in[7];
  const float* wxp_im = (const float*)d_in[8];
  const float* W_conv = (const float*)d_in[9];
  const float* phase = (const float*)d_in[10];
  const float* b_nl = (const float*)d_in[11];
  const float* W1 = (const float*)d_in[12];
  const float* b1 = (const float*)d_in[13];
  const float* W2 = (const float*)d_in[14];
  const float* b2 = (const float*)d_in[15];
  const float* W3 = (const float*)d_in[16];
  const float* b3 = (const float*)d_in[17];
  const float* Wres = (const float*)d_in[18];
  const float* bres = (const float*)d_in[19];
  float* out = (float*)d_out;

  int N = in_sizes[0] / 8;
  int E = in_sizes[2] / 2;

  // workspace layout
  float* ws = (float*)d_ws;
  int* pay5 = (int*)ws;                               // 5E ints
  float* g2f = ws + (size_t)E * 5;                    // 288N floats
  float2* g2 = (float2*)g2f;
  float* h1_g = g2f;                                  // N*128; g dead by mlp1
  float* y = g2f + (size_t)N * 288;                   // N*16
  float* yebuf_f = y + (size_t)N * 16;                // E*16 floats; desc_g aliases
  float2* yebuf = (float2*)yebuf_f;
  float* desc_g = yebuf_f;                            // N*296 <= E*16; ye dead by then
  int* cnt = (int*)(yebuf_f + (size_t)E * 16);        // N
  int* offs = cnt + N;                                // N+1
  int* scnt = offs + N + 1;                           // N
  int* soffs = scnt + N;                              // N+1
  int* rank = soffs + N + 1;                          // E
  int* srank = rank + E;                              // E
  int2* scomb = (int2*)(srank + E);                   // E int2

  hipMemsetAsync(cnt, 0, (size_t)N * sizeof(int), stream);
  hipMemsetAsync(scnt, 0, (size_t)N * sizeof(int), stream);

  g_kernel<<<(N * 72 + 255) / 256, 256, 0, stream>>>(x_re, x_im, W_conv, phase, g2, N);
  count_kernel<<<(E + 255) / 256, 256, 0, stream>>>(edges, cnt, scnt, rank, srank, E);
  scan_dual_kernel<<<1, 1024, 0, stream>>>(cnt, offs, scnt, soffs, N);
  fill_kernel<<<(E + 255) / 256, 256, 0, stream>>>(edges, offs, soffs, rank, srank,
                                                   wxp_re, wxp_im, ln_re, ln_im,
                                                   pay5, scomb, E);
  conv_src_kernel<<<(N + 3) / 4, 256, 0, stream>>>(soffs, scomb, sten_re,
                                                   sten_im, g2, yebuf, N);
  ye_reduce_kernel<<<(N + 3) / 4, 256, 0, stream>>>(offs, yebuf, b_nl, y, N);
  hist_kernel<<<(N + 7) / 8, 256, 0, stream>>>(offs, pay5, y, desc_g, N);
  mlp1_kernel<<<(N + 63) / 64, 256, 0, stream>>>(desc_g, W1, b1, h1_g, N);
  mlp23_kernel<<<(N + 63) / 64, 256, 0, stream>>>(h1_g, x_re, x_im, W2, b2,
                                                  W3, b3, Wres, bres, out, N);
}

// Round 21
// 400.279 us; speedup vs baseline: 1.0326x; 1.0326x over previous
//
#include <hip/hip_runtime.h>
#include <math.h>

#define EPSF 1e-6f

__device__ __constant__ int DISK[37] = {
    2, 3, 4,
    8, 9, 10, 11, 12,
    14, 15, 16, 17, 18, 19, 20,
    21, 22, 23, 24, 25, 26, 27,
    28, 29, 30, 31, 32, 33, 34,
    36, 37, 38, 39, 40,
    44, 45, 46};

// ---------------------------------------------------------------------------
// g[n, d, rm] = sum_c Wc[d, c, rm] * x[n, c];  Wc = W_conv * exp(i*phase)
// v2: each thread computes 2 adjacent rm (one float4 store).
// ---------------------------------------------------------------------------
__global__ __launch_bounds__(256) void g_kernel(
    const float* __restrict__ x_re, const float* __restrict__ x_im,
    const float* __restrict__ W_conv, const float* __restrict__ phase,
    float2* __restrict__ g2, int N) {
  __shared__ float wc_re[1152];
  __shared__ float wc_im[1152];
  int t = threadIdx.x;
  for (int i = t; i < 1152; i += 256) {
    int dc = i / 18;
    float w = W_conv[i];
    float ph = phase[dc];
    wc_re[i] = w * cosf(ph);
    wc_im[i] = w * sinf(ph);
  }
  __syncthreads();
  int gid = blockIdx.x * 256 + t;
  int total = N * 72;  // (n, d, p) pairs; each covers rm=2p, 2p+1
  if (gid >= total) return;
  int n = gid / 72;
  int q = gid - n * 72;  // d*9 + p
  int d = q / 9;
  int p = q - d * 9;
  int rm = 2 * p;
  const float* xr = x_re + n * 8;
  const float* xi = x_im + n * 8;
  float ar0 = 0.f, ai0 = 0.f, ar1 = 0.f, ai1 = 0.f;
#pragma unroll
  for (int c = 0; c < 8; ++c) {
    int base = (d * 8 + c) * 18 + rm;
    float vr = xr[c], vi = xi[c];
    float wr0 = wc_re[base], wi0 = wc_im[base];
    ar0 += wr0 * vr - wi0 * vi;
    ai0 += wr0 * vi + wi0 * vr;
    float wr1 = wc_re[base + 1], wi1 = wc_im[base + 1];
    ar1 += wr1 * vr - wi1 * vi;
    ai1 += wr1 * vi + wi1 * vr;
  }
  float4 outv = make_float4(ar0, ai0, ar1, ai1);
  *(float4*)(g2 + (size_t)n * 144 + d * 18 + rm) = outv;
}

// ---------------------------------------------------------------------------
// CSR build: count degrees AND capture each edge's rank within its bucket.
// ---------------------------------------------------------------------------
__global__ __launch_bounds__(256) void count_kernel(const int* __restrict__ edges,
                                                    int* __restrict__ cnt,
                                                    int* __restrict__ scnt,
                                                    int* __restrict__ rank,
                                                    int* __restrict__ srank, int E) {
  int e = blockIdx.x * 256 + threadIdx.x;
  if (e >= E) return;
  int2 ed = ((const int2*)edges)[e];
  rank[e] = atomicAdd(&cnt[ed.y], 1);
  srank[e] = atomicAdd(&scnt[ed.x], 1);
}

// Single-block dual exclusive scan: cnt->offs and scnt->soffs
__global__ __launch_bounds__(1024) void scan_dual_kernel(
    const int* __restrict__ cnt, int* __restrict__ offs,
    const int* __restrict__ scnt, int* __restrict__ soffs, int N) {
  __shared__ int sums[1024];
  int t = threadIdx.x;
  int per = (N + 1023) / 1024;
  for (int pass = 0; pass < 2; ++pass) {
    const int* c = pass ? scnt : cnt;
    int* o = pass ? soffs : offs;
    int base = t * per;
    int s = 0;
    for (int i = 0; i < per; ++i) {
      int idx = base + i;
      if (idx < N) s += c[idx];
    }
    sums[t] = s;
    __syncthreads();
    for (int d = 1; d < 1024; d <<= 1) {
      int v = (t >= d) ? sums[t - d] : 0;
      __syncthreads();
      sums[t] += v;
      __syncthreads();
    }
    int run = (t == 0) ? 0 : sums[t - 1];
    for (int i = 0; i < per; ++i) {
      int idx = base + i;
      if (idx < N) {
        int cc = c[idx];
        o[idx] = run;
        run += cc;
      }
    }
    if (t == 1023) o[N] = sums[1023];
    __syncthreads();
  }
}

// fill: atomic-free pure scatter with non-temporal stores.
__global__ __launch_bounds__(256) void fill_kernel(
    const int* __restrict__ edges, const int* __restrict__ offs,
    const int* __restrict__ soffs, const int* __restrict__ rank,
    const int* __restrict__ srank,
    const float* __restrict__ wxp_re, const float* __restrict__ wxp_im,
    const float* __restrict__ ln_re, const float* __restrict__ ln_im,
    int* __restrict__ pay5, int2* __restrict__ scomb, int E) {
  int e = blockIdx.x * 256 + threadIdx.x;
  if (e >= E) return;
  int2 ed = ((const int2*)edges)[e];
  int pos = offs[ed.y] + rank[e];
  int pos2 = soffs[ed.x] + srank[e];
  int* p = pay5 + (size_t)pos * 5;
  __builtin_nontemporal_store(ed.x, p);
  __builtin_nontemporal_store(__float_as_int(wxp_re[e]), p + 1);
  __builtin_nontemporal_store(__float_as_int(wxp_im[e]), p + 2);
  __builtin_nontemporal_store(__float_as_int(ln_re[e]), p + 3);
  __builtin_nontemporal_store(__float_as_int(ln_im[e]), p + 4);
  int2 sc = make_int2(e, pos);
  __builtin_nontemporal_store(*(long long*)&sc, (long long*)(scomb + pos2));
}

// ---------------------------------------------------------------------------
// Edge conv, src-grouped (R18-exact: 1-deep scomb prefetch, (256,4)).
// Measured best: 79.5us, no spill, Occ ~45%.
// ---------------------------------------------------------------------------
__global__ __launch_bounds__(256, 4) void conv_src_kernel(
    const int* __restrict__ soffs, const int2* __restrict__ scomb,
    const float* __restrict__ sten_re, const float* __restrict__ sten_im,
    const float2* __restrict__ g2, float2* __restrict__ yebuf, int N) {
  int t = threadIdx.x;
  int m = blockIdx.x * 4 + (t >> 6);
  if (m >= N) return;
  int lane = t & 63;
  int es = lane >> 3;
  int d = lane & 7;
  float gr[18], gi[18];
  const float4* gq = (const float4*)(g2 + (size_t)m * 144 + d * 18);
#pragma unroll
  for (int p = 0; p < 9; ++p) {
    float4 v = gq[p];
    gr[2 * p] = v.x; gi[2 * p] = v.y;
    gr[2 * p + 1] = v.z; gi[2 * p + 1] = v.w;
  }
  int beg = soffs[m], end = soffs[m + 1];
  int i = beg + es;
  if (i >= end) return;
  int2 sc = scomb[i];
  for (; i < end; i += 8) {
    int2 cur = sc;
    if (i + 8 < end) sc = scomb[i + 8];  // prefetch next slot early
    int e = cur.x;
    int ds = cur.y;
    const float* br = sten_re + (size_t)e * 18;
    const float* bi = sten_im + (size_t)e * 18;
    float4 r0 = *(const float4*)(br);
    float4 r1 = *(const float4*)(br + 4);
    float4 r2 = *(const float4*)(br + 8);
    float4 r3 = *(const float4*)(br + 12);
    float2 r4 = *(const float2*)(br + 16);
    float4 m0 = *(const float4*)(bi);
    float4 m1 = *(const float4*)(bi + 4);
    float4 m2 = *(const float4*)(bi + 8);
    float4 m3 = *(const float4*)(bi + 12);
    float2 m4 = *(const float2*)(bi + 16);
    float sr[18], si[18];
    sr[0] = r0.x; sr[1] = r0.y; sr[2] = r0.z; sr[3] = r0.w;
    sr[4] = r1.x; sr[5] = r1.y; sr[6] = r1.z; sr[7] = r1.w;
    sr[8] = r2.x; sr[9] = r2.y; sr[10] = r2.z; sr[11] = r2.w;
    sr[12] = r3.x; sr[13] = r3.y; sr[14] = r3.z; sr[15] = r3.w;
    sr[16] = r4.x; sr[17] = r4.y;
    si[0] = m0.x; si[1] = m0.y; si[2] = m0.z; si[3] = m0.w;
    si[4] = m1.x; si[5] = m1.y; si[6] = m1.z; si[7] = m1.w;
    si[8] = m2.x; si[9] = m2.y; si[10] = m2.z; si[11] = m2.w;
    si[12] = m3.x; si[13] = m3.y; si[14] = m3.z; si[15] = m3.w;
    si[16] = m4.x; si[17] = m4.y;
    float ar = 0.f, ai = 0.f;
#pragma unroll
    for (int rm = 0; rm < 18; ++rm) {
      ar += sr[rm] * gr[rm] - si[rm] * gi[rm];
      ai += sr[rm] * gi[rm] + si[rm] * gr[rm];
    }
    float2 v = make_float2(ar, ai);
    __builtin_nontemporal_store(*(long long*)&v,
                                (long long*)(yebuf + (size_t)ds * 8 + d));
  }
}

// ---------------------------------------------------------------------------
// Reduce ye over each node's contiguous dst-slot range + nonlinearity -> y.
// ---------------------------------------------------------------------------
__global__ __launch_bounds__(256, 4) void ye_reduce_kernel(
    const int* __restrict__ offs, const float2* __restrict__ yebuf,
    const float* __restrict__ b_nl, float* __restrict__ y, int N) {
  int t = threadIdx.x;
  int n = blockIdx.x * 4 + (t >> 6);
  if (n >= N) return;
  int lane = t & 63;
  int es = lane >> 3;
  int d = lane & 7;
  int beg = offs[n], end = offs[n + 1];
  float ar = 0.f, ai = 0.f;
  for (int i = beg + es; i < end; i += 8) {
    long long raw = __builtin_nontemporal_load(
        (const long long*)(yebuf + (size_t)i * 8 + d));
    float2 v = *(float2*)&raw;
    ar += v.x;
    ai += v.y;
  }
  ar += __shfl_xor(ar, 8);
  ai += __shfl_xor(ai, 8);
  ar += __shfl_xor(ar, 16);
  ai += __shfl_xor(ai, 16);
  ar += __shfl_xor(ar, 32);
  ai += __shfl_xor(ai, 32);
  if (lane < 8) {
    float mag = sqrtf(ar * ar + ai * ai);
    float s = fmaxf(mag + b_nl[d], 0.f) / (mag + EPSF);
    y[(size_t)n * 16 + 2 * d] = ar * s;
    y[(size_t)n * 16 + 2 * d + 1] = ai * s;
  }
}

// ---------------------------------------------------------------------------
// Histogram, ZERO FP atomics: per-thread exclusive 51-word LDS strip.
// ---------------------------------------------------------------------------
__global__ __launch_bounds__(256, 3) void hist_kernel(
    const int* __restrict__ offs, const int* __restrict__ pay5,
    const float* __restrict__ y, float* __restrict__ desc_g, int N) {
  __shared__ float hl[256 * 51];  // 52.2 KB
  int t = threadIdx.x;
  int n0 = blockIdx.x * 8;
  for (int i = t; i < 256 * 51; i += 256) hl[i] = 0.f;
  __syncthreads();

  int v = t >> 5;
  int es = (t >> 3) & 3;
  int d = t & 7;
  int n = n0 + v;
  float* hd = hl + (size_t)t * 51;
  if (n < N) {
    int beg = offs[n], end = offs[n + 1];
    for (int i = beg + es; i < end; i += 4) {
      const int* p = pay5 + (size_t)i * 5;
      int src = p[0];
      float wr = __int_as_float(p[1]);
      float wi = __int_as_float(p[2]);
      float lr = __int_as_float(p[3]);
      float li = __int_as_float(p[4]);
      float2 yv = *(const float2*)(y + (size_t)src * 16 + 2 * d);
      float yr = yv.x, yi = yv.y;
      float fr = yr * wr - yi * wi;
      float fi = yr * wi + yi * wr;
      float fm = sqrtf(fr * fr + fi * fi);
      float inv = 1.f / (fm + EPSF);
      float cr = (lr * fr + li * fi) * inv;
      float ci = (li * fr - lr * fi) * inv;
      float gx = cr * 3.f + 3.f;
      float gy = ci * 3.f + 3.f;
      float x0f = floorf(gx), y0f = floorf(gy);
      float wx = gx - x0f, wy = gy - y0f;
      int x0i = min(max((int)x0f, 0), 6);
      int x1i = min(x0i + 1, 6);
      int y0i = min(max((int)y0f, 0), 6);
      int y1i = min(y0i + 1, 6);
      hd[x0i * 7 + y0i] += fm * (1.f - wx) * (1.f - wy);
      hd[x1i * 7 + y0i] += fm * wx * (1.f - wy);
      hd[x0i * 7 + y1i] += fm * (1.f - wx) * wy;
      hd[x1i * 7 + y1i] += fm * wx * wy;
    }
  }
  __syncthreads();

  for (int i = t; i < 8 * 296; i += 256) {
    int vv = i / 296;
    int q = i - vv * 296;
    int dd = q / 37;
    int k = q - dd * 37;
    int bin = DISK[k];
    float s = 0.f;
#pragma unroll
    for (int e2 = 0; e2 < 4; ++e2)
      s += hl[(size_t)(vv * 32 + e2 * 8 + dd) * 51 + bin];
    int nn = n0 + vv;
    if (nn < N) desc_g[(size_t)nn * 296 + q] = s;
  }
}

// ---------------------------------------------------------------------------
// mlp1: h1 = relu(desc @ W1^T + b1).  64 nodes/block, 256 threads.
// kk loop pinned no-unroll (prevents unroll-and-hoist spill; R13 verified).
// ---------------------------------------------------------------------------
__global__ __launch_bounds__(256, 4) void mlp1_kernel(
    const float* __restrict__ desc_g, const float* __restrict__ W1,
    const float* __restrict__ b1, float* __restrict__ h1_g, int N) {
  __shared__ float bufA[64 * 40];
  __shared__ float bufB[40 * 133];
  int t = threadIdx.x;
  int n0 = blockIdx.x * 64;
  int jt = t & 31;
  int nb = (t >> 5) * 8;

  float acc[8][4];
#pragma unroll
  for (int jj = 0; jj < 4; ++jj) {
    float bb = b1[jt + 32 * jj];
#pragma unroll
    for (int i = 0; i < 8; ++i) acc[i][jj] = bb;
  }

  for (int k0 = 0; k0 < 296; k0 += 40) {
    int kc = min(40, 296 - k0);
    int kc4 = kc >> 2;
    for (int i = t; i < 64 * kc4; i += 256) {
      int r = i / kc4, c4 = (i - r * kc4) * 4;
      int n = n0 + r;
      float4 v = (n < N) ? *(const float4*)&desc_g[(size_t)n * 296 + k0 + c4]
                         : make_float4(0.f, 0.f, 0.f, 0.f);
      *(float4*)&bufA[r * 40 + c4] = v;
    }
    for (int i = t; i < 128 * kc4; i += 256) {
      int r = i / kc4, c4 = (i - r * kc4) * 4;
      float4 w = *(const float4*)&W1[(size_t)r * 296 + k0 + c4];
      bufB[(c4 + 0) * 133 + r] = w.x;
      bufB[(c4 + 1) * 133 + r] = w.y;
      bufB[(c4 + 2) * 133 + r] = w.z;
      bufB[(c4 + 3) * 133 + r] = w.w;
    }
    __syncthreads();
#pragma unroll 1
    for (int kk = 0; kk < kc; kk += 4) {
      float4 a[8];
#pragma unroll
      for (int i = 0; i < 8; ++i) a[i] = *(const float4*)&bufA[(nb + i) * 40 + kk];
#pragma unroll
      for (int q = 0; q < 4; ++q) {
        float bv[4];
#pragma unroll
        for (int jj = 0; jj < 4; ++jj) bv[jj] = bufB[(kk + q) * 133 + jt + 32 * jj];
#pragma unroll
        for (int i = 0; i < 8; ++i) {
          float av = (q == 0) ? a[i].x : (q == 1) ? a[i].y : (q == 2) ? a[i].z : a[i].w;
#pragma unroll
          for (int jj = 0; jj < 4; ++jj) acc[i][jj] += av * bv[jj];
        }
      }
    }
    __syncthreads();
  }
#pragma unroll
  for (int i = 0; i < 8; ++i) {
    int n = n0 + nb + i;
    if (n < N) {
#pragma unroll
      for (int jj = 0; jj < 4; ++jj)
        h1_g[(size_t)n * 128 + jt + 32 * jj] = fmaxf(acc[i][jj], 0.f);
    }
  }
}

// ---------------------------------------------------------------------------
// mlp23 (R7/R11 structure): separate h2s buffer; kk loops pinned no-unroll.
// ---------------------------------------------------------------------------
__global__ __launch_bounds__(256, 4) void mlp23_kernel(
    const float* __restrict__ h1_g,
    const float* __restrict__ x_re, const float* __restrict__ x_im,
    const float* __restrict__ W2, const float* __restrict__ b2,
    const float* __restrict__ W3, const float* __restrict__ b3,
    const float* __restrict__ Wres, const float* __restrict__ bres,
    float* __restrict__ out, int N) {
  __shared__ float bufA[64 * 68];
  __shared__ float bufB[64 * 67];
  __shared__ float h2s[64 * 68];
  __shared__ float rmag[64][8];
  int t = threadIdx.x;
  int n0 = blockIdx.x * 64;
  int jt = t & 31;
  int nb = (t >> 5) * 8;

  for (int i = t; i < 512; i += 256) {
    int v = i >> 3, c = i & 7;
    int n = n0 + v;
    if (n < N) {
      float xr = x_re[n * 8 + c], xi = x_im[n * 8 + c];
      rmag[v][c] = sqrtf(xr * xr + xi * xi + EPSF);
    } else {
      rmag[v][c] = 0.f;
    }
  }

  // ---------------- Layer 2 ----------------
  float acc2[8][2];
#pragma unroll
  for (int jj = 0; jj < 2; ++jj) {
    float bb = b2[jt + 32 * jj];
#pragma unroll
    for (int i = 0; i < 8; ++i) acc2[i][jj] = bb;
  }
#pragma unroll 1
  for (int k0 = 0; k0 < 128; k0 += 64) {
    for (int i = t; i < 64 * 16; i += 256) {
      int r = i >> 4, c4 = (i & 15) * 4;
      int n = n0 + r;
      float4 v = (n < N) ? *(const float4*)&h1_g[(size_t)n * 128 + k0 + c4]
                         : make_float4(0.f, 0.f, 0.f, 0.f);
      *(float4*)&bufA[r * 68 + c4] = v;
    }
    for (int i = t; i < 64 * 16; i += 256) {
      int r = i >> 4, c4 = (i & 15) * 4;
      float4 w = *(const float4*)&W2[(size_t)r * 128 + k0 + c4];
      bufB[(c4 + 0) * 67 + r] = w.x;
      bufB[(c4 + 1) * 67 + r] = w.y;
      bufB[(c4 + 2) * 67 + r] = w.z;
      bufB[(c4 + 3) * 67 + r] = w.w;
    }
    __syncthreads();
#pragma unroll 1
    for (int kk = 0; kk < 64; kk += 4) {
      float4 a[8];
#pragma unroll
      for (int i = 0; i < 8; ++i) a[i] = *(const float4*)&bufA[(nb + i) * 68 + kk];
#pragma unroll
      for (int q = 0; q < 4; ++q) {
        float bv[2];
#pragma unroll
        for (int jj = 0; jj < 2; ++jj) bv[jj] = bufB[(kk + q) * 67 + jt + 32 * jj];
#pragma unroll
        for (int i = 0; i < 8; ++i) {
          float av = (q == 0) ? a[i].x : (q == 1) ? a[i].y : (q == 2) ? a[i].z : a[i].w;
#pragma unroll
          for (int jj = 0; jj < 2; ++jj) acc2[i][jj] += av * bv[jj];
        }
      }
    }
    __syncthreads();
  }
#pragma unroll
  for (int i = 0; i < 8; ++i)
#pragma unroll
    for (int jj = 0; jj < 2; ++jj)
      h2s[(nb + i) * 68 + jt + 32 * jj] = fmaxf(acc2[i][jj], 0.f);

  // stage W3 k-major (reuse bufB)
  __syncthreads();
  for (int i = t; i < 64 * 16; i += 256) {
    int r = i >> 4, c4 = (i & 15) * 4;
    float4 w = *(const float4*)&W3[(size_t)r * 64 + c4];
    bufB[(c4 + 0) * 67 + r] = w.x;
    bufB[(c4 + 1) * 67 + r] = w.y;
    bufB[(c4 + 2) * 67 + r] = w.z;
    bufB[(c4 + 3) * 67 + r] = w.w;
  }
  __syncthreads();

  // ---------------- Layer 3 + residual ----------------
  float acc3[8][2];
#pragma unroll
  for (int jj = 0; jj < 2; ++jj) {
    float bb = b3[jt + 32 * jj] + bres[jt + 32 * jj];
#pragma unroll
    for (int i = 0; i < 8; ++i) acc3[i][jj] = bb;
  }
#pragma unroll 1
  for (int kk = 0; kk < 64; kk += 4) {
    float4 a[8];
#pragma unroll
    for (int i = 0; i < 8; ++i) a[i] = *(const float4*)&h2s[(nb + i) * 68 + kk];
#pragma unroll
    for (int q = 0; q < 4; ++q) {
      float bv[2];
#pragma unroll
      for (int jj = 0; jj < 2; ++jj) bv[jj] = bufB[(kk + q) * 67 + jt + 32 * jj];
#pragma unroll
      for (int i = 0; i < 8; ++i) {
        float av = (q == 0) ? a[i].x : (q == 1) ? a[i].y : (q == 2) ? a[i].z : a[i].w;
#pragma unroll
        for (int jj = 0; jj < 2; ++jj) acc3[i][jj] += av * bv[jj];
      }
    }
  }
#pragma unroll
  for (int jj = 0; jj < 2; ++jj) {
    int j = jt + 32 * jj;
    float wrr[8];
    const float* wp = Wres + (size_t)j * 8;
#pragma unroll
    for (int c = 0; c < 8; ++c) wrr[c] = wp[c];
#pragma unroll
    for (int i = 0; i < 8; ++i) {
      float s = acc3[i][jj];
#pragma unroll
      for (int c = 0; c < 8; ++c) s += wrr[c] * rmag[nb + i][c];
      int n = n0 + nb + i;
      if (n < N) out[(size_t)n * 64 + j] = s;
    }
  }
}

extern "C" void kernel_launch(void* const* d_in, const int* in_sizes, int n_in,
                              void* d_out, int out_size, void* d_ws, size_t ws_size,
                              hipStream_t stream) {
  (void)n_in; (void)out_size; (void)ws_size;
  const float* x_re = (const float*)d_in[0];
  const float* x_im = (const float*)d_in[1];
  const int* edges = (const int*)d_in[2];
  const float* sten_re = (const float*)d_in[3];
  const float* sten_im = (const float*)d_in[4];
  const float* ln_re = (const float*)d_in[5];
  const float* ln_im = (const float*)d_in[6];
  const float* wxp_re = (const float*)d_in[7];
  const float* wxp_im = (const float*)d_in[8];
  const float* W_conv = (const float*)d_in[9];
  const float* phase = (const float*)d_in[10];
  const float* b_nl = (const float*)d_in[11];
  const float* W1 = (const float*)d_in[12];
  const float* b1 = (const float*)d_in[13];
  const float* W2 = (const float*)d_in[14];
  const float* b2 = (const float*)d_in[15];
  const float* W3 = (const float*)d_in[16];
  const float* b3 = (const float*)d_in[17];
  const float* Wres = (const float*)d_in[18];
  const float* bres = (const float*)d_in[19];
  float* out = (float*)d_out;

  int N = in_sizes[0] / 8;
  int E = in_sizes[2] / 2;

  // workspace layout
  float* ws = (float*)d_ws;
  int* pay5 = (int*)ws;                               // 5E ints
  float* g2f = ws + (size_t)E * 5;                    // 288N floats
  float2* g2 = (float2*)g2f;
  float* h1_g = g2f;                                  // N*128; g dead by mlp1
  float* y = g2f + (size_t)N * 288;                   // N*16
  float* yebuf_f = y + (size_t)N * 16;                // E*16 floats; desc_g aliases
  float2* yebuf = (float2*)yebuf_f;
  float* desc_g = yebuf_f;                            // N*296 <= E*16; ye dead by then
  int* cnt = (int*)(yebuf_f + (size_t)E * 16);        // N
  int* offs = cnt + N;                                // N+1
  int* scnt = offs + N + 1;                           // N
  int* soffs = scnt + N;                              // N+1
  int* rank = soffs + N + 1;                          // E
  int* srank = rank + E;                              // E
  int2* scomb = (int2*)(srank + E);                   // E int2

  hipMemsetAsync(cnt, 0, (size_t)N * sizeof(int), stream);
  hipMemsetAsync(scnt, 0, (size_t)N * sizeof(int), stream);

  g_kernel<<<(N * 72 + 255) / 256, 256, 0, stream>>>(x_re, x_im, W_conv, phase, g2, N);
  count_kernel<<<(E + 255) / 256, 256, 0, stream>>>(edges, cnt, scnt, rank, srank, E);
  scan_dual_kernel<<<1, 1024, 0, stream>>>(cnt, offs, scnt, soffs, N);
  fill_kernel<<<(E + 255) / 256, 256, 0, stream>>>(edges, offs, soffs, rank, srank,
                                                   wxp_re, wxp_im, ln_re, ln_im,
                                                   pay5, scomb, E);
  conv_src_kernel<<<(N + 3) / 4, 256, 0, stream>>>(soffs, scomb, sten_re,
                                                   sten_im, g2, yebuf, N);
  ye_reduce_kernel<<<(N + 3) / 4, 256, 0, stream>>>(offs, yebuf, b_nl, y, N);
  hist_kernel<<<(N + 7) / 8, 256, 0, stream>>>(offs, pay5, y, desc_g, N);
  mlp1_kernel<<<(N + 63) / 64, 256, 0, stream>>>(desc_g, W1, b1, h1_g, N);
  mlp23_kernel<<<(N + 63) / 64, 256, 0, stream>>>(h1_g, x_re, x_im, W2, b2,
                                                  W3, b3, Wres, bres, out, N);
}